// Round 1
// baseline (1278.510 us; speedup 1.0000x reference)
//
#include <hip/hip_runtime.h>
#include <hip/hip_bf16.h>
#include <math.h>

#define PI4F 0.78539816339744830962f

// ---------------- Kernel 1: global average pool ----------------
// x: [8,64,128,128] -> pooled [512]
__global__ void k_pool(const float* __restrict__ x, float* __restrict__ pooled) {
    int bc = blockIdx.x;                 // 0..511
    const float* p = x + (size_t)bc * 16384;
    float s = 0.f;
    for (int j = threadIdx.x; j < 16384; j += 256) s += p[j];
    // wave64 reduce
    for (int off = 32; off > 0; off >>= 1) s += __shfl_xor(s, off, 64);
    __shared__ float red[4];
    int wave = threadIdx.x >> 6;
    if ((threadIdx.x & 63) == 0) red[wave] = s;
    __syncthreads();
    if (threadIdx.x == 0) {
        float t = red[0] + red[1] + red[2] + red[3];
        pooled[bc] = t * (1.0f / 16384.0f);
    }
}

// ---------------- Kernel 2: small MLPs -> angles, mod ----------------
// grid 32 = (i*8+b), block 64
__global__ void k_mlp(const float* __restrict__ pooled,
                      const float* __restrict__ aw1, const float* __restrict__ ab1,
                      const float* __restrict__ aw2, const float* __restrict__ ab2,
                      const float* __restrict__ mw1, const float* __restrict__ mb1,
                      const float* __restrict__ mw2, const float* __restrict__ mb2,
                      float* __restrict__ angles, float* __restrict__ mod) {
    int i = blockIdx.x >> 3, b = blockIdx.x & 7;
    int t = threadIdx.x;
    __shared__ float sp[64], sha[16], shm[16];
    sp[t] = pooled[b * 64 + t];
    __syncthreads();
    if (t < 16) {
        float sa = ab1[i * 16 + t], sm = mb1[i * 16 + t];
        const float* wa = aw1 + ((size_t)i * 16 + t) * 64;
        const float* wm = mw1 + ((size_t)i * 16 + t) * 64;
        for (int c = 0; c < 64; ++c) { sa = fmaf(wa[c], sp[c], sa); sm = fmaf(wm[c], sp[c], sm); }
        sha[t] = fmaxf(sa, 0.f);
        shm[t] = fmaxf(sm, 0.f);
    }
    __syncthreads();
    if (t < 8) {
        float s = ab2[i * 8 + t];
        const float* w = aw2 + ((size_t)i * 8 + t) * 16;
        for (int j = 0; j < 16; ++j) s = fmaf(w[j], sha[j], s);
        angles[i * 64 + b * 8 + t] = tanhf(s) * PI4F;
    }
    {
        float s = mb2[i * 64 + t];
        const float* w = mw2 + ((size_t)i * 64 + t) * 16;
        for (int j = 0; j < 16; ++j) s = fmaf(w[j], shm[j], s);
        mod[i * 512 + b * 64 + t] = 1.f / (1.f + expf(-s));
    }
}

// ---------------- Kernel 3: rotate base kernels ----------------
// grid 256 = ((i*8+b)*8+g), block 64 (co,ci)
// bk: [4,8,8,8,3,3]; rot out: [4][8][8][co][ci][9]
__global__ void k_rot(const float* __restrict__ bk, const float* __restrict__ angles,
                      float* __restrict__ rot) {
    int blk = blockIdx.x;
    int g = blk & 7, b = (blk >> 3) & 7, i = blk >> 6;
    float ang = angles[i * 64 + b * 8 + g];
    float st, ct;
    sincosf(ang, &st, &ct);
    int t = threadIdx.x;
    int co = t >> 3, ci = t & 7;
    const float* K = bk + ((((size_t)i * 8 + g) * 8 + co) * 8 + ci) * 9;
    float* R = rot + ((((size_t)i * 8 + b) * 8 + g) * 64 + t) * 9;
    for (int p = 0; p < 9; ++p) {
        int ky = p / 3, kx = p % 3;
        float xx = (float)kx - 1.f, yy = (float)ky - 1.f;
        float xr = xx * ct + yy * st + 1.f;
        float yr = -xx * st + yy * ct + 1.f;
        float x0 = fminf(fmaxf(floorf(xr), 0.f), 1.f);
        float y0 = fminf(fmaxf(floorf(yr), 0.f), 1.f);
        float x1 = x0 + 1.f, y1 = y0 + 1.f;
        float w00 = (x1 - xr) * (y1 - yr);
        float w01 = (x1 - xr) * (yr - y0);
        float w10 = (xr - x0) * (y1 - yr);
        float w11 = (xr - x0) * (yr - y0);
        int x0i = (int)x0, y0i = (int)y0;
        float v = w00 * K[y0i * 3 + x0i] + w01 * K[(y0i + 1) * 3 + x0i]
                + w10 * K[y0i * 3 + x0i + 1] + w11 * K[(y0i + 1) * 3 + x0i + 1];
        R[p] = v;
    }
}

// ---------------- Kernel 4: grouped rotated conv + mod gate ----------------
// grid (64, 512, 4) = (h/2, b*64+c, branch); block (128,2)
__global__ void __launch_bounds__(256) k_conv(const float* __restrict__ x,
                       const float* __restrict__ rot, const float* __restrict__ mod,
                       float* __restrict__ bf) {
    int i = blockIdx.z;
    int bc = blockIdx.y;
    int b = bc >> 6, c = bc & 63;
    int g = c >> 3;
    int h = blockIdx.x * 2 + threadIdx.y;
    int w = threadIdx.x;

    __shared__ float wgt[72];
    int t = threadIdx.y * 128 + threadIdx.x;
    if (t < 72) {
        size_t rbase = ((((size_t)(i * 8 + b) * 8 + g) * 64) + (size_t)(c & 7) * 8) * 9;
        wgt[t] = rot[rbase + t];
    }
    __syncthreads();

    float mv = mod[i * 512 + b * 64 + c];
    float acc = 0.f;
    const float* xb = x + ((size_t)b * 64 + (size_t)g * 8) * 16384;
#pragma unroll
    for (int ci = 0; ci < 8; ++ci) {
        const float* xp = xb + (size_t)ci * 16384;
#pragma unroll
        for (int ky = 0; ky < 3; ++ky) {
            int hh = h + ky - 1;
            if (hh < 0 || hh > 127) continue;
            const float* row = xp + hh * 128;
#pragma unroll
            for (int kx = 0; kx < 3; ++kx) {
                int ww = w + kx - 1;
                if (ww < 0 || ww > 127) continue;
                acc = fmaf(wgt[ci * 9 + ky * 3 + kx], row[ww], acc);
            }
        }
    }
    bf[((size_t)(i * 8 + b) * 64 + c) * 16384 + h * 128 + w] = acc * mv;
}

// ---------------- Kernel 5: fused epilogue ----------------
// thread-per-pixel; grid 512 x 256
__global__ void __launch_bounds__(256) k_mega(
    const float* __restrict__ x, const float* __restrict__ bfeat,
    const float* __restrict__ roi,
    const float* __restrict__ w1, const float* __restrict__ bnw, const float* __restrict__ bnb,
    const float* __restrict__ bnm, const float* __restrict__ bnv,
    const float* __restrict__ w2, const float* __restrict__ b2,
    const float* __restrict__ ew1, const float* __restrict__ ebnw, const float* __restrict__ ebnb,
    const float* __restrict__ ebnm, const float* __restrict__ ebnv,
    const float* __restrict__ ew2, const float* __restrict__ eb2,
    float* __restrict__ out) {

    __shared__ float sw[4096];      // w1 chunk, transposed [j][o]
    __shared__ float sew1[2048];    // [32][64]
    __shared__ float sew2[2048];    // [64][32]
    __shared__ float sw2[256];      // [4][64]
    __shared__ float sa[64], sd[64];    // dir bn scale / shift
    __shared__ float sea[32], sed[32];  // edge bn scale / shift
    __shared__ float seb2[64];
    __shared__ float sb2x[4];

    int tid = threadIdx.x;
    for (int q = tid; q < 2048; q += 256) sew1[q] = ew1[q];
    for (int q = tid; q < 2048; q += 256) sew2[q] = ew2[q];
    if (tid < 256) sw2[tid] = w2[tid];
    if (tid < 64) {
        float sc = bnw[tid] * rsqrtf(bnv[tid] + 1e-5f);
        sa[tid] = sc;
        sd[tid] = bnb[tid] - bnm[tid] * sc;
        seb2[tid] = eb2[tid];
    }
    if (tid < 32) {
        float sc = ebnw[tid] * rsqrtf(ebnv[tid] + 1e-5f);
        sea[tid] = sc;
        sed[tid] = ebnb[tid] - ebnm[tid] * sc;
    }
    if (tid < 4) sb2x[tid] = b2[tid];

    int p = blockIdx.x * 256 + tid;
    int b = p >> 14;
    int hw = p & 16383;
    int h = hw >> 7, w = hw & 127;

    // ---- phase 1: y = dir_w1 @ feats_cat ----
    float y[64];
#pragma unroll
    for (int o = 0; o < 64; ++o) y[o] = 0.f;
    for (int ch = 0; ch < 4; ++ch) {
        __syncthreads();
        for (int t = tid; t < 4096; t += 256) {
            int o = t & 63, j = t >> 6;
            sw[t] = w1[o * 256 + ch * 64 + j];
        }
        __syncthreads();
        const float* fbi = bfeat + ((size_t)ch * 512 + (size_t)b * 64) * 16384 + hw;
        for (int j = 0; j < 64; ++j) {
            float fv = fbi[(size_t)j * 16384];
            const float4* swv = (const float4*)(sw + j * 64);
#pragma unroll
            for (int o4 = 0; o4 < 16; ++o4) {
                float4 wv = swv[o4];
                y[o4 * 4 + 0] = fmaf(wv.x, fv, y[o4 * 4 + 0]);
                y[o4 * 4 + 1] = fmaf(wv.y, fv, y[o4 * 4 + 1]);
                y[o4 * 4 + 2] = fmaf(wv.z, fv, y[o4 * 4 + 2]);
                y[o4 * 4 + 3] = fmaf(wv.w, fv, y[o4 * 4 + 3]);
            }
        }
    }
    // bn + relu
#pragma unroll
    for (int o = 0; o < 64; ++o) y[o] = fmaxf(fmaf(y[o], sa[o], sd[o]), 0.f);

    // ---- phase 2: logits + softmax ----
    float lg[4];
#pragma unroll
    for (int k = 0; k < 4; ++k) {
        float s = sb2x[k];
        const float4* wv4 = (const float4*)(sw2 + k * 64);
#pragma unroll
        for (int o4 = 0; o4 < 16; ++o4) {
            float4 wv = wv4[o4];
            s = fmaf(wv.x, y[o4 * 4 + 0], s);
            s = fmaf(wv.y, y[o4 * 4 + 1], s);
            s = fmaf(wv.z, y[o4 * 4 + 2], s);
            s = fmaf(wv.w, y[o4 * 4 + 3], s);
        }
        lg[k] = s;
    }
    float mx = fmaxf(fmaxf(lg[0], lg[1]), fmaxf(lg[2], lg[3]));
    float e0 = expf(lg[0] - mx), e1s = expf(lg[1] - mx), e2s = expf(lg[2] - mx), e3s = expf(lg[3] - mx);
    float inv = 1.f / (e0 + e1s + e2s + e3s);
    float a0 = e0 * inv, a1 = e1s * inv, a2 = e2s * inv, a3 = e3s * inv;

    // ---- phase 3: roi bilinear (align_corners) ----
    float ysv = (float)h * (63.f / 127.f);
    float y0f = fminf(floorf(ysv), 62.f);
    float wy = ysv - y0f;
    float xsv = (float)w * (63.f / 127.f);
    float x0f = fminf(floorf(xsv), 62.f);
    float wx = xsv - x0f;
    int y0i = (int)y0f, x0i = (int)x0f;
    const float* rb = roi + (size_t)b * 4096;
    float r00 = rb[y0i * 64 + x0i], r01 = rb[y0i * 64 + x0i + 1];
    float r10 = rb[(y0i + 1) * 64 + x0i], r11 = rb[(y0i + 1) * 64 + x0i + 1];
    float rv = r00 * (1.f - wy) * (1.f - wx) + r01 * (1.f - wy) * wx
             + r10 * wy * (1.f - wx) + r11 * wy * wx;

    // ---- phase 4: fused = sum_i bf_i * attn_i, scaled by roi ----
    float f[64];
    {
        const float* p0 = bfeat + ((size_t)b * 64) * 16384 + hw;
#pragma unroll
        for (int cc = 0; cc < 64; ++cc) {
            const float* pp = p0 + (size_t)cc * 16384;
            float s = a0 * pp[0]
                    + a1 * pp[(size_t)512 * 16384]
                    + a2 * pp[(size_t)1024 * 16384]
                    + a3 * pp[(size_t)1536 * 16384];
            f[cc] = s * rv;
        }
    }

    // ---- phase 5: edge MLP ----
    float eh[32];
#pragma unroll
    for (int o = 0; o < 32; ++o) {
        float s = 0.f;
        const float4* wv4 = (const float4*)(sew1 + o * 64);
#pragma unroll
        for (int c4 = 0; c4 < 16; ++c4) {
            float4 wv = wv4[c4];
            s = fmaf(wv.x, f[c4 * 4 + 0], s);
            s = fmaf(wv.y, f[c4 * 4 + 1], s);
            s = fmaf(wv.z, f[c4 * 4 + 2], s);
            s = fmaf(wv.w, f[c4 * 4 + 3], s);
        }
        eh[o] = fmaxf(fmaf(s, sea[o], sed[o]), 0.f);
    }

    // ---- phase 6: e2 = sigmoid(ew2 @ eh + b), out = x*(1+e2) ----
    const float* xp = x + ((size_t)b * 64) * 16384 + hw;
    float* op = out + ((size_t)b * 64) * 16384 + hw;
#pragma unroll
    for (int cc = 0; cc < 64; ++cc) {
        float s = seb2[cc];
        const float4* wv4 = (const float4*)(sew2 + cc * 32);
#pragma unroll
        for (int o4 = 0; o4 < 8; ++o4) {
            float4 wv = wv4[o4];
            s = fmaf(wv.x, eh[o4 * 4 + 0], s);
            s = fmaf(wv.y, eh[o4 * 4 + 1], s);
            s = fmaf(wv.z, eh[o4 * 4 + 2], s);
            s = fmaf(wv.w, eh[o4 * 4 + 3], s);
        }
        float sg = 1.f / (1.f + expf(-s));
        float xv = xp[(size_t)cc * 16384];
        op[(size_t)cc * 16384] = xv + xv * sg;
    }
}

extern "C" void kernel_launch(void* const* d_in, const int* in_sizes, int n_in,
                              void* d_out, int out_size, void* d_ws, size_t ws_size,
                              hipStream_t stream) {
    const float* x    = (const float*)d_in[0];
    const float* roi  = (const float*)d_in[1];
    const float* bk   = (const float*)d_in[2];
    const float* aw1  = (const float*)d_in[3];
    const float* ab1  = (const float*)d_in[4];
    const float* aw2  = (const float*)d_in[5];
    const float* ab2  = (const float*)d_in[6];
    const float* mw1  = (const float*)d_in[7];
    const float* mb1  = (const float*)d_in[8];
    const float* mw2  = (const float*)d_in[9];
    const float* mb2  = (const float*)d_in[10];
    const float* w1   = (const float*)d_in[11];
    const float* bnw  = (const float*)d_in[12];
    const float* bnb  = (const float*)d_in[13];
    const float* bnm  = (const float*)d_in[14];
    const float* bnv  = (const float*)d_in[15];
    const float* w2   = (const float*)d_in[16];
    const float* b2   = (const float*)d_in[17];
    const float* ew1  = (const float*)d_in[18];
    const float* ebnw = (const float*)d_in[19];
    const float* ebnb = (const float*)d_in[20];
    const float* ebnm = (const float*)d_in[21];
    const float* ebnv = (const float*)d_in[22];
    const float* ew2  = (const float*)d_in[23];
    const float* eb2  = (const float*)d_in[24];

    float* ws     = (float*)d_ws;
    float* pooled = ws;              // 512
    float* angles = ws + 512;        // 256
    float* mod    = ws + 768;        // 2048
    float* rot    = ws + 2816;       // 147456
    float* bfeat  = ws + 150272;     // 4*8*64*16384 = 33554432

    k_pool<<<512, 256, 0, stream>>>(x, pooled);
    k_mlp<<<32, 64, 0, stream>>>(pooled, aw1, ab1, aw2, ab2, mw1, mb1, mw2, mb2, angles, mod);
    k_rot<<<256, 64, 0, stream>>>(bk, angles, rot);
    k_conv<<<dim3(64, 512, 4), dim3(128, 2), 0, stream>>>(x, rot, mod, bfeat);
    k_mega<<<512, 256, 0, stream>>>(x, bfeat, roi,
                                    w1, bnw, bnb, bnm, bnv, w2, b2,
                                    ew1, ebnw, ebnb, ebnm, ebnv, ew2, eb2,
                                    (float*)d_out);
}

// Round 2
// 455.003 us; speedup vs baseline: 2.8099x; 2.8099x over previous
//
#include <hip/hip_runtime.h>
#include <hip/hip_bf16.h>
#include <math.h>

#define PI4F 0.78539816339744830962f

// ---------------- Kernel 1: global average pool ----------------
// x: [8,64,128,128] -> pooled [512]
__global__ void k_pool(const float* __restrict__ x, float* __restrict__ pooled) {
    int bc = blockIdx.x;                 // 0..511
    const float* p = x + (size_t)bc * 16384;
    float s = 0.f;
    for (int j = threadIdx.x; j < 16384; j += 256) s += p[j];
    for (int off = 32; off > 0; off >>= 1) s += __shfl_xor(s, off, 64);
    __shared__ float red[4];
    int wave = threadIdx.x >> 6;
    if ((threadIdx.x & 63) == 0) red[wave] = s;
    __syncthreads();
    if (threadIdx.x == 0) {
        float t = red[0] + red[1] + red[2] + red[3];
        pooled[bc] = t * (1.0f / 16384.0f);
    }
}

// ---------------- Kernel 2: small MLPs -> angles, mod ----------------
__global__ void k_mlp(const float* __restrict__ pooled,
                      const float* __restrict__ aw1, const float* __restrict__ ab1,
                      const float* __restrict__ aw2, const float* __restrict__ ab2,
                      const float* __restrict__ mw1, const float* __restrict__ mb1,
                      const float* __restrict__ mw2, const float* __restrict__ mb2,
                      float* __restrict__ angles, float* __restrict__ mod) {
    int i = blockIdx.x >> 3, b = blockIdx.x & 7;
    int t = threadIdx.x;
    __shared__ float sp[64], sha[16], shm[16];
    sp[t] = pooled[b * 64 + t];
    __syncthreads();
    if (t < 16) {
        float sa = ab1[i * 16 + t], sm = mb1[i * 16 + t];
        const float* wa = aw1 + ((size_t)i * 16 + t) * 64;
        const float* wm = mw1 + ((size_t)i * 16 + t) * 64;
        for (int c = 0; c < 64; ++c) { sa = fmaf(wa[c], sp[c], sa); sm = fmaf(wm[c], sp[c], sm); }
        sha[t] = fmaxf(sa, 0.f);
        shm[t] = fmaxf(sm, 0.f);
    }
    __syncthreads();
    if (t < 8) {
        float s = ab2[i * 8 + t];
        const float* w = aw2 + ((size_t)i * 8 + t) * 16;
        for (int j = 0; j < 16; ++j) s = fmaf(w[j], sha[j], s);
        angles[i * 64 + b * 8 + t] = tanhf(s) * PI4F;
    }
    {
        float s = mb2[i * 64 + t];
        const float* w = mw2 + ((size_t)i * 64 + t) * 16;
        for (int j = 0; j < 16; ++j) s = fmaf(w[j], shm[j], s);
        mod[i * 512 + b * 64 + t] = 1.f / (1.f + expf(-s));
    }
}

// ---------------- Kernel 3: rotate base kernels ----------------
// grid 256 = ((i*8+b)*8+g), block 64 (co,ci)
// bk: [4,8,8,8,3,3]; rot out: [4][8][8][co][ci][9]
__global__ void k_rot(const float* __restrict__ bk, const float* __restrict__ angles,
                      float* __restrict__ rot) {
    int blk = blockIdx.x;
    int g = blk & 7, b = (blk >> 3) & 7, i = blk >> 6;
    float ang = angles[i * 64 + b * 8 + g];
    float st, ct;
    sincosf(ang, &st, &ct);
    int t = threadIdx.x;
    int co = t >> 3, ci = t & 7;
    const float* K = bk + ((((size_t)i * 8 + g) * 8 + co) * 8 + ci) * 9;
    float* R = rot + ((((size_t)i * 8 + b) * 8 + g) * 64 + t) * 9;
    for (int p = 0; p < 9; ++p) {
        int ky = p / 3, kx = p % 3;
        float xx = (float)kx - 1.f, yy = (float)ky - 1.f;
        float xr = xx * ct + yy * st + 1.f;
        float yr = -xx * st + yy * ct + 1.f;
        float x0 = fminf(fmaxf(floorf(xr), 0.f), 1.f);
        float y0 = fminf(fmaxf(floorf(yr), 0.f), 1.f);
        float x1 = x0 + 1.f, y1 = y0 + 1.f;
        float w00 = (x1 - xr) * (y1 - yr);
        float w01 = (x1 - xr) * (yr - y0);
        float w10 = (xr - x0) * (y1 - yr);
        float w11 = (xr - x0) * (yr - y0);
        int x0i = (int)x0, y0i = (int)y0;
        float v = w00 * K[y0i * 3 + x0i] + w01 * K[(y0i + 1) * 3 + x0i]
                + w10 * K[y0i * 3 + x0i + 1] + w11 * K[(y0i + 1) * 3 + x0i + 1];
        R[p] = v;
    }
}

// ---------------- Kernel 4 (v2): tiled grouped rotated conv + mod gate ----------------
// grid (16, 64, 4) = (tile, b*8+g, branch); block 256
// LDS: 8 input channels x 34x34 halo tile. Each thread: 4 rows x 1 col x 8 co.
__global__ void __launch_bounds__(256) k_conv(const float* __restrict__ x,
                       const float* __restrict__ rot, const float* __restrict__ mod,
                       float* __restrict__ bf) {
    __shared__ float s_in[8 * 34 * 34];   // 36992 B

    int i = blockIdx.z;
    int bg = blockIdx.y;
    int b = bg >> 3, g = bg & 7;
    int tile_h0 = (blockIdx.x >> 2) * 32;
    int tile_w0 = (blockIdx.x & 3) * 32;
    int tid = threadIdx.x;

    // ---- stage input tile (with halo, zero-padded) ----
    const float* xg = x + ((size_t)b * 64 + (size_t)g * 8) * 16384;
    for (int idx = tid; idx < 8 * 1156; idx += 256) {
        int ci = idx / 1156;
        int rem = idx - ci * 1156;
        int r = rem / 34;
        int c = rem - r * 34;
        int gh = tile_h0 + r - 1;
        int gw = tile_w0 + c - 1;
        float v = 0.f;
        if (gh >= 0 && gh < 128 && gw >= 0 && gw < 128)
            v = xg[(size_t)ci * 16384 + gh * 128 + gw];
        s_in[idx] = v;
    }
    __syncthreads();

    int lc = tid & 31;          // column within tile
    int lr0 = (tid >> 5) * 4;   // first of 4 rows

    // weights: wave-uniform -> scalar loads
    const float* wbase = rot + ((size_t)(i * 8 + b) * 8 + g) * 576;

    float acc[8][4];
#pragma unroll
    for (int co = 0; co < 8; ++co)
#pragma unroll
        for (int p = 0; p < 4; ++p) acc[co][p] = 0.f;

#pragma unroll
    for (int ci = 0; ci < 8; ++ci) {
        float v[6][3];
        int base = ci * 1156 + lr0 * 34 + lc;
#pragma unroll
        for (int r = 0; r < 6; ++r)
#pragma unroll
            for (int c = 0; c < 3; ++c)
                v[r][c] = s_in[base + r * 34 + c];

#pragma unroll
        for (int co = 0; co < 8; ++co) {
            const float* wp = wbase + (co * 8 + ci) * 9;   // uniform -> SGPR
#pragma unroll
            for (int ky = 0; ky < 3; ++ky)
#pragma unroll
                for (int kx = 0; kx < 3; ++kx) {
                    float wv = wp[ky * 3 + kx];
#pragma unroll
                    for (int p = 0; p < 4; ++p)
                        acc[co][p] = fmaf(wv, v[p + ky][kx], acc[co][p]);
                }
        }
    }

    // ---- store with mod gating ----
#pragma unroll
    for (int co = 0; co < 8; ++co) {
        int c = g * 8 + co;
        float mv = mod[i * 512 + b * 64 + c];   // uniform
        float* op = bf + ((size_t)(i * 8 + b) * 64 + c) * 16384;
#pragma unroll
        for (int p = 0; p < 4; ++p) {
            int gh = tile_h0 + lr0 + p;
            op[gh * 128 + tile_w0 + lc] = acc[co][p] * mv;
        }
    }
}

// ---------------- Kernel 5: fused epilogue ----------------
// thread-per-pixel; grid 512 x 256
__global__ void __launch_bounds__(256) k_mega(
    const float* __restrict__ x, const float* __restrict__ bfeat,
    const float* __restrict__ roi,
    const float* __restrict__ w1, const float* __restrict__ bnw, const float* __restrict__ bnb,
    const float* __restrict__ bnm, const float* __restrict__ bnv,
    const float* __restrict__ w2, const float* __restrict__ b2,
    const float* __restrict__ ew1, const float* __restrict__ ebnw, const float* __restrict__ ebnb,
    const float* __restrict__ ebnm, const float* __restrict__ ebnv,
    const float* __restrict__ ew2, const float* __restrict__ eb2,
    float* __restrict__ out) {

    __shared__ float sw[4096];      // w1 chunk, transposed [j][o]
    __shared__ float sew1[2048];    // [32][64]
    __shared__ float sew2[2048];    // [64][32]
    __shared__ float sw2[256];      // [4][64]
    __shared__ float sa[64], sd[64];
    __shared__ float sea[32], sed[32];
    __shared__ float seb2[64];
    __shared__ float sb2x[4];

    int tid = threadIdx.x;
    for (int q = tid; q < 2048; q += 256) sew1[q] = ew1[q];
    for (int q = tid; q < 2048; q += 256) sew2[q] = ew2[q];
    if (tid < 256) sw2[tid] = w2[tid];
    if (tid < 64) {
        float sc = bnw[tid] * rsqrtf(bnv[tid] + 1e-5f);
        sa[tid] = sc;
        sd[tid] = bnb[tid] - bnm[tid] * sc;
        seb2[tid] = eb2[tid];
    }
    if (tid < 32) {
        float sc = ebnw[tid] * rsqrtf(ebnv[tid] + 1e-5f);
        sea[tid] = sc;
        sed[tid] = ebnb[tid] - ebnm[tid] * sc;
    }
    if (tid < 4) sb2x[tid] = b2[tid];

    int p = blockIdx.x * 256 + tid;
    int b = p >> 14;
    int hw = p & 16383;
    int h = hw >> 7, w = hw & 127;

    // ---- phase 1: y = dir_w1 @ feats_cat ----
    float y[64];
#pragma unroll
    for (int o = 0; o < 64; ++o) y[o] = 0.f;
    for (int ch = 0; ch < 4; ++ch) {
        __syncthreads();
        for (int t = tid; t < 4096; t += 256) {
            int o = t & 63, j = t >> 6;
            sw[t] = w1[o * 256 + ch * 64 + j];
        }
        __syncthreads();
        const float* fbi = bfeat + ((size_t)ch * 512 + (size_t)b * 64) * 16384 + hw;
        for (int j = 0; j < 64; ++j) {
            float fv = fbi[(size_t)j * 16384];
            const float4* swv = (const float4*)(sw + j * 64);
#pragma unroll
            for (int o4 = 0; o4 < 16; ++o4) {
                float4 wv = swv[o4];
                y[o4 * 4 + 0] = fmaf(wv.x, fv, y[o4 * 4 + 0]);
                y[o4 * 4 + 1] = fmaf(wv.y, fv, y[o4 * 4 + 1]);
                y[o4 * 4 + 2] = fmaf(wv.z, fv, y[o4 * 4 + 2]);
                y[o4 * 4 + 3] = fmaf(wv.w, fv, y[o4 * 4 + 3]);
            }
        }
    }
#pragma unroll
    for (int o = 0; o < 64; ++o) y[o] = fmaxf(fmaf(y[o], sa[o], sd[o]), 0.f);

    // ---- phase 2: logits + softmax ----
    float lg[4];
#pragma unroll
    for (int k = 0; k < 4; ++k) {
        float s = sb2x[k];
        const float4* wv4 = (const float4*)(sw2 + k * 64);
#pragma unroll
        for (int o4 = 0; o4 < 16; ++o4) {
            float4 wv = wv4[o4];
            s = fmaf(wv.x, y[o4 * 4 + 0], s);
            s = fmaf(wv.y, y[o4 * 4 + 1], s);
            s = fmaf(wv.z, y[o4 * 4 + 2], s);
            s = fmaf(wv.w, y[o4 * 4 + 3], s);
        }
        lg[k] = s;
    }
    float mx = fmaxf(fmaxf(lg[0], lg[1]), fmaxf(lg[2], lg[3]));
    float e0 = expf(lg[0] - mx), e1s = expf(lg[1] - mx), e2s = expf(lg[2] - mx), e3s = expf(lg[3] - mx);
    float inv = 1.f / (e0 + e1s + e2s + e3s);
    float a0 = e0 * inv, a1 = e1s * inv, a2 = e2s * inv, a3 = e3s * inv;

    // ---- phase 3: roi bilinear (align_corners) ----
    float ysv = (float)h * (63.f / 127.f);
    float y0f = fminf(floorf(ysv), 62.f);
    float wy = ysv - y0f;
    float xsv = (float)w * (63.f / 127.f);
    float x0f = fminf(floorf(xsv), 62.f);
    float wx = xsv - x0f;
    int y0i = (int)y0f, x0i = (int)x0f;
    const float* rb = roi + (size_t)b * 4096;
    float r00 = rb[y0i * 64 + x0i], r01 = rb[y0i * 64 + x0i + 1];
    float r10 = rb[(y0i + 1) * 64 + x0i], r11 = rb[(y0i + 1) * 64 + x0i + 1];
    float rv = r00 * (1.f - wy) * (1.f - wx) + r01 * (1.f - wy) * wx
             + r10 * wy * (1.f - wx) + r11 * wy * wx;

    // ---- phase 4: fused = sum_i bf_i * attn_i, scaled by roi ----
    float f[64];
    {
        const float* p0 = bfeat + ((size_t)b * 64) * 16384 + hw;
#pragma unroll
        for (int cc = 0; cc < 64; ++cc) {
            const float* pp = p0 + (size_t)cc * 16384;
            float s = a0 * pp[0]
                    + a1 * pp[(size_t)512 * 16384]
                    + a2 * pp[(size_t)1024 * 16384]
                    + a3 * pp[(size_t)1536 * 16384];
            f[cc] = s * rv;
        }
    }

    // ---- phase 5: edge MLP ----
    float eh[32];
#pragma unroll
    for (int o = 0; o < 32; ++o) {
        float s = 0.f;
        const float4* wv4 = (const float4*)(sew1 + o * 64);
#pragma unroll
        for (int c4 = 0; c4 < 16; ++c4) {
            float4 wv = wv4[c4];
            s = fmaf(wv.x, f[c4 * 4 + 0], s);
            s = fmaf(wv.y, f[c4 * 4 + 1], s);
            s = fmaf(wv.z, f[c4 * 4 + 2], s);
            s = fmaf(wv.w, f[c4 * 4 + 3], s);
        }
        eh[o] = fmaxf(fmaf(s, sea[o], sed[o]), 0.f);
    }

    // ---- phase 6: e2 = sigmoid(ew2 @ eh + b), out = x*(1+e2) ----
    const float* xp = x + ((size_t)b * 64) * 16384 + hw;
    float* op = out + ((size_t)b * 64) * 16384 + hw;
#pragma unroll
    for (int cc = 0; cc < 64; ++cc) {
        float s = seb2[cc];
        const float4* wv4 = (const float4*)(sew2 + cc * 32);
#pragma unroll
        for (int o4 = 0; o4 < 8; ++o4) {
            float4 wv = wv4[o4];
            s = fmaf(wv.x, eh[o4 * 4 + 0], s);
            s = fmaf(wv.y, eh[o4 * 4 + 1], s);
            s = fmaf(wv.z, eh[o4 * 4 + 2], s);
            s = fmaf(wv.w, eh[o4 * 4 + 3], s);
        }
        float sg = 1.f / (1.f + expf(-s));
        float xv = xp[(size_t)cc * 16384];
        op[(size_t)cc * 16384] = xv + xv * sg;
    }
}

extern "C" void kernel_launch(void* const* d_in, const int* in_sizes, int n_in,
                              void* d_out, int out_size, void* d_ws, size_t ws_size,
                              hipStream_t stream) {
    const float* x    = (const float*)d_in[0];
    const float* roi  = (const float*)d_in[1];
    const float* bk   = (const float*)d_in[2];
    const float* aw1  = (const float*)d_in[3];
    const float* ab1  = (const float*)d_in[4];
    const float* aw2  = (const float*)d_in[5];
    const float* ab2  = (const float*)d_in[6];
    const float* mw1  = (const float*)d_in[7];
    const float* mb1  = (const float*)d_in[8];
    const float* mw2  = (const float*)d_in[9];
    const float* mb2  = (const float*)d_in[10];
    const float* w1   = (const float*)d_in[11];
    const float* bnw  = (const float*)d_in[12];
    const float* bnb  = (const float*)d_in[13];
    const float* bnm  = (const float*)d_in[14];
    const float* bnv  = (const float*)d_in[15];
    const float* w2   = (const float*)d_in[16];
    const float* b2   = (const float*)d_in[17];
    const float* ew1  = (const float*)d_in[18];
    const float* ebnw = (const float*)d_in[19];
    const float* ebnb = (const float*)d_in[20];
    const float* ebnm = (const float*)d_in[21];
    const float* ebnv = (const float*)d_in[22];
    const float* ew2  = (const float*)d_in[23];
    const float* eb2  = (const float*)d_in[24];

    float* ws     = (float*)d_ws;
    float* pooled = ws;              // 512
    float* angles = ws + 512;        // 256
    float* mod    = ws + 768;        // 2048
    float* rot    = ws + 2816;       // 147456
    float* bfeat  = ws + 150272;     // 4*8*64*16384 = 33554432

    k_pool<<<512, 256, 0, stream>>>(x, pooled);
    k_mlp<<<32, 64, 0, stream>>>(pooled, aw1, ab1, aw2, ab2, mw1, mb1, mw2, mb2, angles, mod);
    k_rot<<<256, 64, 0, stream>>>(bk, angles, rot);
    k_conv<<<dim3(16, 64, 4), 256, 0, stream>>>(x, rot, mod, bfeat);
    k_mega<<<512, 256, 0, stream>>>(x, bfeat, roi,
                                    w1, bnw, bnb, bnm, bnv, w2, b2,
                                    ew1, ebnw, ebnb, ebnm, ebnv, ew2, eb2,
                                    (float*)d_out);
}